// Round 4
// baseline (180.845 us; speedup 1.0000x reference)
//
#include <hip/hip_runtime.h>

namespace {

constexpr int L = 3264;
constexpr int K = 12;
constexpr int S = 8;
constexpr int B = 64;
constexpr int A = 4;
constexpr int R = 816;            // L / LOCC
constexpr int NOFF = 21;          // delays -10..10
constexpr int PEAK_STEP = L / K;  // 272
constexpr float TWO_PI = 6.28318530717958647692f;
constexpr float CINV = TWO_PI / (float)L;
constexpr int NCHUNK = (L + 255) / 256;  // 13

__device__ __forceinline__ float rfl(float x) {
    return __uint_as_float(__builtin_amdgcn_readfirstlane(__float_as_uint(x)));
}

// ---------------------------------------------------------------------------
// Kernel 0: twiddle table tw[j] = e^{+i*2*pi*j/L}, 26 KB, L1-resident later.
// ---------------------------------------------------------------------------
__global__ __launch_bounds__(256)
void k_table(float2* __restrict__ tw)
{
    const int j = blockIdx.x * 256 + threadIdx.x;
    if (j < L) {
        float sv, cv;
        __sincosf(CINV * (float)j, &sv, &cv);
        tw[j] = make_float2(cv, sv);
    }
}

// ---------------------------------------------------------------------------
// Kernel 1: per (s,b). 8 waves: wave w = antenna w>>1, half w&1 (k stride 128).
// 21 candidate DFT bins via 21 INDEPENDENT register phasors, each rotated by
// a per-bin block-uniform step (SGPR via readfirstlane). No trig in the loop.
// Then ballot-argmax and table-driven OCC-demux average.
// ---------------------------------------------------------------------------
__global__ __launch_bounds__(512)
void k_stage1(const float* __restrict__ lsr, const float* __restrict__ lsi,
              const int* __restrict__ cs, const float2* __restrict__ tw,
              int* __restrict__ toff_out, int* __restrict__ m_out,
              float2* __restrict__ havg)
{
    __shared__ float2 red[8][NOFF];
    __shared__ int m_sh;

    const int sb = blockIdx.x;
    const int s = sb >> 6;
    const int tid = threadIdx.x;
    const int lane = tid & 63;
    const int w = tid >> 6;
    const int a = w >> 1;
    const int h = w & 1;

    const int csv = cs[s];
    const int ideal = ((K - csv) % K) * PEAK_STEP;
    int idx0 = (ideal - 10) % L; if (idx0 < 0) idx0 += L;

    const int k0 = h * 64 + lane;              // starting k, stride 128

    // initial phasors w_d = e^{i*2pi*k0*(idx0+d)/L}
    const int jb = (k0 * idx0) % L;            // <= 414K
    float br, bi; __sincosf(CINV * (float)jb, &bi, &br);
    float lr, li; __sincosf(CINV * (float)k0, &li, &lr);
    float pwr[NOFF], pwi[NOFF];
    pwr[0] = br; pwi[0] = bi;
    #pragma unroll
    for (int d = 1; d < NOFF; ++d) {
        pwr[d] = pwr[d-1] * lr - pwi[d-1] * li;
        pwi[d] = pwr[d-1] * li + pwi[d-1] * lr;
    }

    // per-bin steps e^{i*2pi*128*(idx0+d)/L} — block-uniform -> SGPR
    const int js = (128 * idx0) % L;
    float s0r, s0i; __sincosf(CINV * (float)js, &s0i, &s0r);
    float e8r, e8i; __sincosf(CINV * 128.0f, &e8i, &e8r);
    float str_[NOFF], sti_[NOFF];
    {
        float cr = s0r, ci = s0i;
        #pragma unroll
        for (int d = 0; d < NOFF; ++d) {
            str_[d] = rfl(cr); sti_[d] = rfl(ci);
            const float nr = cr * e8r - ci * e8i;
            ci = cr * e8i + ci * e8r;
            cr = nr;
        }
    }

    const size_t rowbase = ((size_t)sb * A + a) * L;
    const float* __restrict__ pr = lsr + rowbase;
    const float* __restrict__ pi_ = lsi + rowbase;

    float ar[NOFF], ai[NOFF];
    #pragma unroll
    for (int d = 0; d < NOFF; ++d) { ar[d] = 0.f; ai[d] = 0.f; }

    for (int it = 0; it < 25; ++it) {          // k = k0 + 128*it <= 3199
        const float xr = pr[k0 + (it << 7)];
        const float xi = pi_[k0 + (it << 7)];
        #pragma unroll
        for (int d = 0; d < NOFF; ++d) {
            ar[d] += xr * pwr[d] - xi * pwi[d];
            ai[d] += xr * pwi[d] + xi * pwr[d];
            const float nr = pwr[d] * str_[d] - pwi[d] * sti_[d];
            pwi[d] = pwr[d] * sti_[d] + pwi[d] * str_[d];
            pwr[d] = nr;
        }
    }
    if (k0 < 64) {                             // tail k = k0 + 3200 < 3264
        const float xr = pr[k0 + 3200];
        const float xi = pi_[k0 + 3200];
        #pragma unroll
        for (int d = 0; d < NOFF; ++d) {
            ar[d] += xr * pwr[d] - xi * pwi[d];
            ai[d] += xr * pwi[d] + xi * pwr[d];
        }
    }

    #pragma unroll
    for (int d = 0; d < NOFF; ++d) {
        float r = ar[d], im = ai[d];
        #pragma unroll
        for (int o = 32; o > 0; o >>= 1) {
            r  += __shfl_xor(r, o);
            im += __shfl_xor(im, o);
        }
        if (lane == 0) red[w][d] = make_float2(r, im);
    }
    __syncthreads();

    if (w == 0) {
        float pw = -1.f;
        if (lane < NOFF) {
            pw = 0.f;
            #pragma unroll
            for (int a2 = 0; a2 < A; ++a2) {
                const float2 u = red[2 * a2][lane];
                const float2 v = red[2 * a2 + 1][lane];
                const float rr = u.x + v.x;
                const float ii = u.y + v.y;
                pw += rr * rr + ii * ii;
            }
        }
        float mx = pw;
        #pragma unroll
        for (int o = 32; o > 0; o >>= 1) mx = fmaxf(mx, __shfl_xor(mx, o));
        const unsigned long long msk = __ballot(pw == mx);
        const int argd = __ffsll(msk) - 1;     // first max == jnp.argmax
        if (lane == 0) {
            const int toff = argd - 10;
            toff_out[sb] = toff;
            m_out[sb]    = toff + ideal;
            m_sh         = toff + ideal;
        }
    }
    __syncthreads();

    int mp = m_sh % L; if (mp < 0) mp += L;
    const float2 emp = tw[mp];                 // uniform in-group rotation

    for (int aa = 0; aa < A; ++aa) {
        const float4* __restrict__ qr4 = (const float4*)(lsr + ((size_t)sb * A + aa) * L);
        const float4* __restrict__ qi4 = (const float4*)(lsi + ((size_t)sb * A + aa) * L);
        float2* __restrict__ dst = havg + ((size_t)sb * A + aa) * R;
        for (int i = tid; i < R; i += 512) {
            const int j = (mp * (4 * i)) % L;  // <= 10.6M, int32 ok
            const float2 w0 = tw[j];
            const float4 xr = qr4[i];
            const float4 xi = qi4[i];
            float wr = w0.x, wi = w0.y;
            float are, aim, nr;
            are  = xr.x * wr - xi.x * wi;  aim  = xr.x * wi + xi.x * wr;
            nr = wr * emp.x - wi * emp.y;  wi = wr * emp.y + wi * emp.x;  wr = nr;
            are += xr.y * wr - xi.y * wi;  aim += xr.y * wi + xi.y * wr;
            nr = wr * emp.x - wi * emp.y;  wi = wr * emp.y + wi * emp.x;  wr = nr;
            are += xr.z * wr - xi.z * wi;  aim += xr.z * wi + xi.z * wr;
            nr = wr * emp.x - wi * emp.y;  wi = wr * emp.y + wi * emp.x;  wr = nr;
            are += xr.w * wr - xi.w * wi;  aim += xr.w * wi + xi.w * wr;
            dst[i] = make_float2(are * 0.25f, aim * 0.25f);
        }
    }
}

// ---------------------------------------------------------------------------
// Kernel 2: per (b,a,l). All phasors from the L1-resident table (exact
// integer phase index) — zero trig.
// ---------------------------------------------------------------------------
__global__ __launch_bounds__(256)
void k_final(const float* __restrict__ lsr, const float* __restrict__ lsi,
             const int* __restrict__ toff_arr, const int* __restrict__ m_arr,
             const float2* __restrict__ havg, const float2* __restrict__ tw,
             float* __restrict__ out)
{
    const int bid = blockIdx.x;
    const int chunk = bid % NCHUNK;
    const int ba = bid / NCHUNK;
    const int b = ba >> 2;
    const int a = ba & 3;
    const int l = chunk * 256 + (int)threadIdx.x;
    if (l >= L) return;

    float t = ((float)l - 1.5f) * 0.25f;
    t = fminf(fmaxf(t, 0.0f), (float)(R - 1));
    const int i0 = (int)t;
    const int i1 = min(i0 + 1, R - 1);
    const float frac = t - (float)i0;

    float hire[S], hiim[S], pmre[S], pmim[S];
    float rre = 0.f, rim = 0.f;

    #pragma unroll
    for (int s = 0; s < S; ++s) {
        const int sb = s * B + b;
        int mp = m_arr[sb] % L; if (mp < 0) mp += L;
        const float2 wm = tw[(mp * l) % L];            // <= 10.65M, int32 ok
        const float2 h0 = havg[((size_t)sb * A + a) * R + i0];
        const float2 h1 = havg[((size_t)sb * A + a) * R + i1];
        const float hr = h0.x * (1.f - frac) + h1.x * frac;
        const float hi = h0.y * (1.f - frac) + h1.y * frac;
        hire[s] = hr; hiim[s] = hi; pmre[s] = wm.x; pmim[s] = wm.y;
        rre += hr * wm.x + hi * wm.y;                  // h * conj(ph_m)
        rim += hi * wm.x - hr * wm.y;
    }

    const size_t off0 = ((size_t)(b * A + a)) * L + l;
    const float resre = lsr[off0] - rre;
    const float resim = lsi[off0] - rim;

    #pragma unroll
    for (int s = 0; s < S; ++s) {
        const float wre = hire[s] + resre * pmre[s] - resim * pmim[s];
        const float wim = hiim[s] + resre * pmim[s] + resim * pmre[s];
        int jt = (toff_arr[s * B + b] * l) % L; if (jt < 0) jt += L;
        const float2 wt = tw[jt];
        const float fre = wre * wt.x + wim * wt.y;     // * conj(ph_T)
        const float fim = wim * wt.x - wre * wt.y;
        const size_t o = (((size_t)(s * B + b)) * A + a) * L + l;
        __builtin_nontemporal_store(fre, &out[o]);
        __builtin_nontemporal_store(fim, &out[(size_t)S * B * A * L + o]);
    }
}

}  // namespace

extern "C" void kernel_launch(void* const* d_in, const int* in_sizes, int n_in,
                              void* d_out, int out_size, void* d_ws, size_t ws_size,
                              hipStream_t stream) {
    (void)in_sizes; (void)n_in; (void)out_size; (void)ws_size;
    const float* lsr = (const float*)d_in[0];
    const float* lsi = (const float*)d_in[1];
    const int*   cs  = (const int*)d_in[2];
    // d_in[3] (noise_powers) unused: mmse_module is identity.

    int* toff = (int*)d_ws;                                  // 512 ints
    int* marr = toff + 512;                                  // 512 ints
    float2* tw = (float2*)((char*)d_ws + 4096);              // 26112 B table
    float2* havg = (float2*)((char*)d_ws + 36864);           // 13.37 MB

    k_table<<<NCHUNK, 256, 0, stream>>>(tw);
    k_stage1<<<S * B, 512, 0, stream>>>(lsr, lsi, cs, tw, toff, marr, havg);
    k_final<<<B * A * NCHUNK, 256, 0, stream>>>(lsr, lsi, toff, marr, havg, tw,
                                                (float*)d_out);
}

// Round 5
// 168.631 us; speedup vs baseline: 1.0724x; 1.0724x over previous
//
#include <hip/hip_runtime.h>

namespace {

constexpr int L = 3264;
constexpr int K = 12;
constexpr int S = 8;
constexpr int B = 64;
constexpr int A = 4;
constexpr int R = 816;            // L / LOCC
constexpr int NOFF = 21;          // delays -10..10
constexpr int PEAK_STEP = L / K;  // 272
constexpr float TWO_PI = 6.28318530717958647692f;
constexpr float CINV = TWO_PI / (float)L;
constexpr int NCHUNK = (L + 255) / 256;  // 13

__device__ __forceinline__ float rfl(float x) {
    return __uint_as_float(__builtin_amdgcn_readfirstlane(__float_as_uint(x)));
}

// ---------------------------------------------------------------------------
// Kernel 0: twiddle table tw[j] = e^{+i*2*pi*j/L} (26 KB in workspace).
// ---------------------------------------------------------------------------
__global__ __launch_bounds__(256)
void k_table(float2* __restrict__ tw)
{
    const int j = blockIdx.x * 256 + threadIdx.x;
    if (j < L) {
        float sv, cv;
        __sincosf(CINV * (float)j, &sv, &cv);
        tw[j] = make_float2(cv, sv);
    }
}

// ---------------------------------------------------------------------------
// Kernel 1a: one block per LS row (s,b,a) -> 2048 blocks, 256 threads.
// 21 candidate DFT bins via 21 independent register phasors rotated by
// block-uniform per-bin steps (SGPR). Writes per-antenna bin power.
// ---------------------------------------------------------------------------
__global__ __launch_bounds__(256)
void k_dft(const float* __restrict__ lsr, const float* __restrict__ lsi,
           const int* __restrict__ cs, float* __restrict__ pow_out)
{
    __shared__ float2 red[4][NOFF];

    const int blk = blockIdx.x;            // row index sb*A + a
    const int sb = blk >> 2;
    const int a = blk & 3;
    const int s = sb >> 6;
    const int tid = threadIdx.x;
    const int lane = tid & 63;
    const int w = tid >> 6;                // wave 0..3

    const int ideal = ((K - cs[s]) % K) * PEAK_STEP;
    int idx0 = (ideal - 10) % L; if (idx0 < 0) idx0 += L;

    // initial phasors w_d = e^{i*2pi*tid*(idx0+d)/L}
    const int jb = (tid * idx0) % L;       // <= 832K
    float br, bi; __sincosf(CINV * (float)jb, &bi, &br);
    float lr, li; __sincosf(CINV * (float)tid, &li, &lr);
    float pwr[NOFF], pwi[NOFF], ar[NOFF], ai[NOFF];
    pwr[0] = br; pwi[0] = bi;
    #pragma unroll
    for (int d = 1; d < NOFF; ++d) {
        pwr[d] = pwr[d-1] * lr - pwi[d-1] * li;
        pwi[d] = pwr[d-1] * li + pwi[d-1] * lr;
    }
    #pragma unroll
    for (int d = 0; d < NOFF; ++d) { ar[d] = 0.f; ai[d] = 0.f; }

    // per-bin k-stride-256 steps e^{i*2pi*256*(idx0+d)/L} — uniform -> SGPR
    const int js = (256 * idx0) % L;
    float s0r, s0i; __sincosf(CINV * (float)js, &s0i, &s0r);
    float c8r, c8i; __sincosf(CINV * 256.0f, &c8i, &c8r);
    float str_[NOFF], sti_[NOFF];
    {
        float cr = s0r, ci = s0i;
        #pragma unroll
        for (int d = 0; d < NOFF; ++d) {
            str_[d] = rfl(cr); sti_[d] = rfl(ci);
            const float nr2 = cr * c8r - ci * c8i;
            ci = cr * c8i + ci * c8r;
            cr = nr2;
        }
    }

    const float* __restrict__ pr  = lsr + (size_t)blk * L;
    const float* __restrict__ pi_ = lsi + (size_t)blk * L;

    for (int it = 0; it < 12; ++it) {      // k = tid + 256*it
        const float xr = pr[tid + (it << 8)];
        const float xi = pi_[tid + (it << 8)];
        #pragma unroll
        for (int d = 0; d < NOFF; ++d) {
            ar[d] += xr * pwr[d] - xi * pwi[d];
            ai[d] += xr * pwi[d] + xi * pwr[d];
            const float nr2 = pwr[d] * str_[d] - pwi[d] * sti_[d];
            pwi[d] = pwr[d] * sti_[d] + pwi[d] * str_[d];
            pwr[d] = nr2;
        }
    }
    if (tid < 192) {                       // tail k = tid + 3072 < 3264
        const float xr = pr[tid + 3072];
        const float xi = pi_[tid + 3072];
        #pragma unroll
        for (int d = 0; d < NOFF; ++d) {
            ar[d] += xr * pwr[d] - xi * pwi[d];
            ai[d] += xr * pwi[d] + xi * pwr[d];
        }
    }

    #pragma unroll
    for (int d = 0; d < NOFF; ++d) {
        float r = ar[d], im = ai[d];
        #pragma unroll
        for (int o = 32; o > 0; o >>= 1) {
            r  += __shfl_xor(r, o);
            im += __shfl_xor(im, o);
        }
        if (lane == 0) red[w][d] = make_float2(r, im);
    }
    __syncthreads();

    if (w == 0 && lane < NOFF) {
        float rr = 0.f, ii = 0.f;
        #pragma unroll
        for (int q = 0; q < 4; ++q) { rr += red[q][lane].x; ii += red[q][lane].y; }
        pow_out[sb * (NOFF * A) + lane * A + a] = rr * rr + ii * ii;
    }
}

// ---------------------------------------------------------------------------
// Kernel 1b: per sb: sum antenna powers, first-max argmax (jnp semantics).
// ---------------------------------------------------------------------------
__global__ __launch_bounds__(64)
void k_argmax(const float* __restrict__ pow_in, const int* __restrict__ cs,
              int* __restrict__ toff_out, int* __restrict__ m_out)
{
    const int sb = blockIdx.x;
    const int lane = threadIdx.x;
    const int s = sb >> 6;
    const int ideal = ((K - cs[s]) % K) * PEAK_STEP;

    float pw = -1.f;
    if (lane < NOFF) {
        const float4 p4 = *(const float4*)(pow_in + sb * (NOFF * A) + lane * A);
        pw = p4.x + p4.y + p4.z + p4.w;
    }
    float mx = pw;
    #pragma unroll
    for (int o = 32; o > 0; o >>= 1) mx = fmaxf(mx, __shfl_xor(mx, o));
    const unsigned long long msk = __ballot(pw == mx);
    const int argd = __ffsll(msk) - 1;     // lowest lane = first max
    if (lane == 0) {
        const int toff = argd - 10;
        toff_out[sb] = toff;
        m_out[sb]    = toff + ideal;
    }
}

// ---------------------------------------------------------------------------
// Kernel 1c: one block per row (s,b,a): OCC-demux average h_avg via table.
// ---------------------------------------------------------------------------
__global__ __launch_bounds__(256)
void k_havg(const float* __restrict__ lsr, const float* __restrict__ lsi,
            const int* __restrict__ m_arr, const float2* __restrict__ tw,
            float2* __restrict__ havg)
{
    const int blk = blockIdx.x;            // row index sb*A + a
    const int sb = blk >> 2;
    const int tid = threadIdx.x;

    int mp = m_arr[sb] % L; if (mp < 0) mp += L;
    const float2 emp = tw[mp];             // uniform in-group rotation

    const float4* __restrict__ qr4 = (const float4*)(lsr + (size_t)blk * L);
    const float4* __restrict__ qi4 = (const float4*)(lsi + (size_t)blk * L);
    float2* __restrict__ dst = havg + (size_t)blk * R;

    for (int i = tid; i < R; i += 256) {
        const int j = (mp * (4 * i)) % L;  // <= 10.6M, int32 ok
        const float2 w0 = tw[j];
        const float4 xr = qr4[i];
        const float4 xi = qi4[i];
        float wr = w0.x, wi = w0.y;
        float are, aim, nr;
        are  = xr.x * wr - xi.x * wi;  aim  = xr.x * wi + xi.x * wr;
        nr = wr * emp.x - wi * emp.y;  wi = wr * emp.y + wi * emp.x;  wr = nr;
        are += xr.y * wr - xi.y * wi;  aim += xr.y * wi + xi.y * wr;
        nr = wr * emp.x - wi * emp.y;  wi = wr * emp.y + wi * emp.x;  wr = nr;
        are += xr.z * wr - xi.z * wi;  aim += xr.z * wi + xi.z * wr;
        nr = wr * emp.x - wi * emp.y;  wi = wr * emp.y + wi * emp.x;  wr = nr;
        are += xr.w * wr - xi.w * wi;  aim += xr.w * wi + xi.w * wr;
        dst[i] = make_float2(are * 0.25f, aim * 0.25f);
    }
}

// ---------------------------------------------------------------------------
// Kernel 2: per (b,a,l). Twiddle table staged in LDS — divergent gathers
// become ds_read_b64 instead of 64-line L1 serialization.
// ---------------------------------------------------------------------------
__global__ __launch_bounds__(256)
void k_final(const float* __restrict__ lsr, const float* __restrict__ lsi,
             const int* __restrict__ toff_arr, const int* __restrict__ m_arr,
             const float2* __restrict__ havg, const float2* __restrict__ tw,
             float* __restrict__ out)
{
    __shared__ float2 twl[L];              // 26112 B
    for (int j = threadIdx.x; j < L; j += 256) twl[j] = tw[j];
    __syncthreads();

    const int bid = blockIdx.x;
    const int chunk = bid % NCHUNK;
    const int ba = bid / NCHUNK;
    const int b = ba >> 2;
    const int a = ba & 3;
    const int l = chunk * 256 + (int)threadIdx.x;
    if (l >= L) return;

    float t = ((float)l - 1.5f) * 0.25f;
    t = fminf(fmaxf(t, 0.0f), (float)(R - 1));
    const int i0 = (int)t;
    const int i1 = min(i0 + 1, R - 1);
    const float frac = t - (float)i0;

    float hire[S], hiim[S], pmre[S], pmim[S];
    float rre = 0.f, rim = 0.f;

    #pragma unroll
    for (int s = 0; s < S; ++s) {
        const int sb = s * B + b;
        int mp = m_arr[sb] % L; if (mp < 0) mp += L;
        const float2 wm = twl[(mp * l) % L];           // <= 10.65M, int32 ok
        const float2 h0 = havg[((size_t)sb * A + a) * R + i0];
        const float2 h1 = havg[((size_t)sb * A + a) * R + i1];
        const float hr = h0.x * (1.f - frac) + h1.x * frac;
        const float hi = h0.y * (1.f - frac) + h1.y * frac;
        hire[s] = hr; hiim[s] = hi; pmre[s] = wm.x; pmim[s] = wm.y;
        rre += hr * wm.x + hi * wm.y;                  // h * conj(ph_m)
        rim += hi * wm.x - hr * wm.y;
    }

    const size_t off0 = ((size_t)(b * A + a)) * L + l;
    const float resre = lsr[off0] - rre;
    const float resim = lsi[off0] - rim;

    #pragma unroll
    for (int s = 0; s < S; ++s) {
        const float wre = hire[s] + resre * pmre[s] - resim * pmim[s];
        const float wim = hiim[s] + resre * pmim[s] + resim * pmre[s];
        int jt = (toff_arr[s * B + b] * l) % L; if (jt < 0) jt += L;
        const float2 wt = twl[jt];
        const float fre = wre * wt.x + wim * wt.y;     // * conj(ph_T)
        const float fim = wim * wt.x - wre * wt.y;
        const size_t o = (((size_t)(s * B + b)) * A + a) * L + l;
        __builtin_nontemporal_store(fre, &out[o]);
        __builtin_nontemporal_store(fim, &out[(size_t)S * B * A * L + o]);
    }
}

}  // namespace

extern "C" void kernel_launch(void* const* d_in, const int* in_sizes, int n_in,
                              void* d_out, int out_size, void* d_ws, size_t ws_size,
                              hipStream_t stream) {
    (void)in_sizes; (void)n_in; (void)out_size; (void)ws_size;
    const float* lsr = (const float*)d_in[0];
    const float* lsi = (const float*)d_in[1];
    const int*   cs  = (const int*)d_in[2];
    // d_in[3] (noise_powers) unused: mmse_module is identity.

    int* toff = (int*)d_ws;                                  // 512 ints @ 0
    int* marr = toff + 512;                                  // 512 ints @ 2048
    float2* tw   = (float2*)((char*)d_ws + 4096);            // 26112 B
    float*  powb = (float*)((char*)d_ws + 30720);            // 512*84*4 B = 168 KB
    float2* havg = (float2*)((char*)d_ws + 204800);          // 13.37 MB

    k_table <<<NCHUNK, 256, 0, stream>>>(tw);
    k_dft   <<<S * B * A, 256, 0, stream>>>(lsr, lsi, cs, powb);
    k_argmax<<<S * B, 64, 0, stream>>>(powb, cs, toff, marr);
    k_havg  <<<S * B * A, 256, 0, stream>>>(lsr, lsi, marr, tw, havg);
    k_final <<<B * A * NCHUNK, 256, 0, stream>>>(lsr, lsi, toff, marr, havg, tw,
                                                 (float*)d_out);
}